// Round 7
// baseline (444.645 us; speedup 1.0000x reference)
//
#include <hip/hip_runtime.h>

#define NU 8192
#define NI 8192
#define DD 128

typedef float fx4 __attribute__((ext_vector_type(4)));
typedef int   ix4 __attribute__((ext_vector_type(4)));
typedef short bx8 __attribute__((ext_vector_type(8)));
typedef short sx4 __attribute__((ext_vector_type(4)));

__device__ __forceinline__ short f2bf(float f) {
  unsigned u = __float_as_uint(f);
  u = (u + 0x7FFFu + ((u >> 16) & 1u)) >> 16;   // RNE f32 -> bf16
  return (short)u;
}
__device__ __forceinline__ float lrelu(float x) { return fmaxf(x, 0.2f * x); }
// order-preserving float<->uint encode for atomicMax (deterministic: max assoc/comm)
__device__ __forceinline__ unsigned fenc(float f) {
  unsigned u = __float_as_uint(f);
  return (u >> 31) ? ~u : (u | 0x80000000u);
}
__device__ __forceinline__ float fdec(unsigned u) {
  return (u >> 31) ? __uint_as_float(u & 0x7FFFFFFFu) : __uint_as_float(~u);
}

// ---- K1: v1[j] = sum_k a[k]*W[k][j] ; v2[j] = sum_k a[128+k]*W[k][j]; init mxenc
__global__ void k_vecs(const float* __restrict__ W, const float* __restrict__ a,
                       float* __restrict__ v1, float* __restrict__ v2,
                       unsigned* __restrict__ mxenc) {
  int j = threadIdx.x;  // 128 threads
  if (j == 0) mxenc[0] = 0u;
  float s1 = 0.f, s2 = 0.f;
  for (int k = 0; k < DD; ++k) {
    float w = W[k * DD + j];
    s1 += a[k] * w;
    s2 += a[DD + k] * w;
  }
  v1[j] = s1; v2[j] = s2;
}

// ---- K2: a1[u]=h_u·v1 ; a2[i]=h_i·v2 ; E1=exp(a2), E2=exp(0.2 a2); atomicMax a2
__global__ __launch_bounds__(256) void k_rowdots(
    const float* __restrict__ hU, const float* __restrict__ hI,
    const float* __restrict__ v1, const float* __restrict__ v2,
    float* __restrict__ a1, float* __restrict__ a2,
    float* __restrict__ e1, float* __restrict__ e2,
    unsigned* __restrict__ mxenc) {
  __shared__ float red[256];
  int g = blockIdx.x * 256 + threadIdx.x;
  const float* h; const float* v; int row;
  bool isU = (g < NU);
  if (isU) { h = hU; v = v1; row = g; }
  else     { h = hI; v = v2; row = g - NU; }
  const fx4* hv = (const fx4*)(h + (size_t)row * DD);
  const fx4* vv = (const fx4*)v;
  float s = 0.f;
#pragma unroll
  for (int q = 0; q < DD / 4; ++q) {
    fx4 hq = hv[q], vq = vv[q];
    s += hq[0]*vq[0] + hq[1]*vq[1] + hq[2]*vq[2] + hq[3]*vq[3];
  }
  if (isU) { a1[row] = s; return; }           // blocks 0..31 all-user: uniform exit
  a2[row] = s;
  e1[row] = __expf(s);
  e2[row] = __expf(0.2f * s);
  red[threadIdx.x] = s;
  __syncthreads();
  for (int st = 128; st > 0; st >>= 1) {
    if (threadIdx.x < st) red[threadIdx.x] = fmaxf(red[threadIdx.x], red[threadIdx.x + st]);
    __syncthreads();
  }
  if (threadIdx.x == 0) atomicMax(mxenc, fenc(red[0]));
}

// ---- K4: WiT[k][i] (bf16) = Wi[i][k] = sum_j h_i[i][j]*W[k][j]
__global__ __launch_bounds__(256) void k_wit(const float* __restrict__ hI,
                                             const float* __restrict__ W,
                                             short* __restrict__ WiT) {
  __shared__ float Wl[128 * 128];
  const int tid = threadIdx.x;
#pragma unroll
  for (int it = 0; it < 16; ++it) {
    int idx = it * 1024 + tid * 4;
    *(fx4*)(Wl + idx) = *(const fx4*)(W + idx);
  }
  __syncthreads();
  const int i0 = blockIdx.x * 64;
  const int rg = tid & 15;
  const int kg = tid >> 4;
  const int r0 = i0 + rg * 4;
  const int k0 = kg * 8;
  float acc[4][8];
#pragma unroll
  for (int r = 0; r < 4; ++r)
#pragma unroll
    for (int c = 0; c < 8; ++c) acc[r][c] = 0.f;
  for (int j = 0; j < 128; j += 4) {
    fx4 wv[8], hv[4];
#pragma unroll
    for (int c = 0; c < 8; ++c) wv[c] = *(const fx4*)(Wl + (k0 + c) * 128 + j);
#pragma unroll
    for (int r = 0; r < 4; ++r) hv[r] = *(const fx4*)(hI + (size_t)(r0 + r) * DD + j);
#pragma unroll
    for (int r = 0; r < 4; ++r)
#pragma unroll
      for (int c = 0; c < 8; ++c)
        acc[r][c] += hv[r][0]*wv[c][0] + hv[r][1]*wv[c][1] + hv[r][2]*wv[c][2] + hv[r][3]*wv[c][3];
  }
#pragma unroll
  for (int c = 0; c < 8; ++c) {
    sx4 pk;
#pragma unroll
    for (int r = 0; r < 4; ++r) pk[r] = f2bf(acc[r][c]);
    *(sx4*)(WiT + (size_t)(k0 + c) * NI + r0) = pk;
  }
}

// ---- K5a v4: adj -> bitmask + rinv. 2 rows/block, grid 4096, deep MLP, no NT.
__global__ __launch_bounds__(512, 4) void k_phaseA(
    const int* __restrict__ adj, const float* __restrict__ a1g,
    const float* __restrict__ e1g, const float* __restrict__ e2g,
    const unsigned* __restrict__ mxenc,
    float* __restrict__ rinv, unsigned short* __restrict__ mask16)
{
  const int tid  = threadIdx.x;
  const int lane = tid & 63;
  const int wv   = tid >> 6;
  const int r0   = blockIdx.x * 2;
  const int i0   = tid * 16;
  const size_t b0 = (size_t)r0 * NI + i0;
  ix4 m0[4], m1[4]; fx4 E1[4], E2[4];
#pragma unroll
  for (int q = 0; q < 4; ++q) m0[q] = *(const ix4*)(adj + b0 + q * 4);
#pragma unroll
  for (int q = 0; q < 4; ++q) m1[q] = *(const ix4*)(adj + b0 + NI + q * 4);
#pragma unroll
  for (int q = 0; q < 4; ++q) {
    E1[q] = *(const fx4*)(e1g + i0 + q * 4);
    E2[q] = *(const fx4*)(e2g + i0 + q * 4);
  }
  const float mA2 = fdec(mxenc[0]);
  const float A0 = a1g[r0], A1 = a1g[r0 + 1];
  const float C0 = lrelu(A0 + mA2),  C1 = lrelu(A1 + mA2);
  const float K10 = __expf(A0 - C0), K11 = __expf(A1 - C1);
  const float K20 = __expf(0.2f * A0 - C0), K21 = __expf(0.2f * A1 - C1);
  const float T10 = __expf(-A0), T11 = __expf(-A1);
  unsigned hw0 = 0u, hw1 = 0u;
  float s10 = 0.f, s20 = 0.f, s11 = 0.f, s21 = 0.f;
#pragma unroll
  for (int q = 0; q < 4; ++q) {
#pragma unroll
    for (int e = 0; e < 4; ++e) {
      const float e1v = E1[q][e], e2v = E2[q][e];
      const bool sel0 = (e1v > T10), sel1 = (e1v > T11);
      const bool a0 = (m0[q][e] != 0), a1m = (m1[q][e] != 0);
      if (a0)  hw0 |= (1u << (q * 4 + e));
      if (a1m) hw1 |= (1u << (q * 4 + e));
      s10 += (a0 && sel0)   ? e1v : 0.f;
      s20 += (a0 && !sel0)  ? e2v : 0.f;
      s11 += (a1m && sel1)  ? e1v : 0.f;
      s21 += (a1m && !sel1) ? e2v : 0.f;
    }
  }
  mask16[(size_t)r0 * 512 + tid]       = (unsigned short)hw0;
  mask16[(size_t)(r0 + 1) * 512 + tid] = (unsigned short)hw1;
  float ps0 = K10 * s10 + K20 * s20;
  float ps1 = K11 * s11 + K21 * s21;
#pragma unroll
  for (int st = 1; st < 64; st <<= 1) {
    ps0 += __shfl_xor(ps0, st, 64);
    ps1 += __shfl_xor(ps1, st, 64);
  }
  __shared__ float lp[2][8];
  if (lane == 0) { lp[0][wv] = ps0; lp[1][wv] = ps1; }
  __syncthreads();
  if (tid < 2) {
    float l = 0.f;
#pragma unroll
    for (int w = 0; w < 8; ++w) l += lp[tid][w];
    rinv[r0 + tid] = (l > 0.f) ? (1.f / l) : 0.f;
  }
}

// ---- K5b: fused alpha + out-partial GEMM, LDS-staged B, sector-clean alpha stores.
// grid 512 = 128 uTiles x 4 K-quarters; 512 thr (8 waves = 4 wm x 2 wn2).
// Block: rows u0..u0+64, i-range quar*2048..+2048. BK=64, 32 chunks, dbuf LDS 32KB.
// Store phase: wave wv stores rows u0+wv*8..+8; each instr = 4 rows x 256B runs.
__global__ __launch_bounds__(512, 6) void k_big(
    const unsigned* __restrict__ mask, const float* __restrict__ a1g,
    const float* __restrict__ e1g, const float* __restrict__ e2g,
    const unsigned* __restrict__ mxenc, const float* __restrict__ rinv,
    const short* __restrict__ WiT, float* __restrict__ partial,
    float* __restrict__ alphap)
{
  __shared__ __align__(16) char lds[32768];
  const int tid  = threadIdx.x;
  const int lane = tid & 63;
  const int wv   = tid >> 6;
  const int wm   = wv & 3;         // m-frag (16 rows each)
  const int wn2  = wv >> 2;        // 0..1: n-half (64 cols each)
  const int uTile = (int)blockIdx.x >> 2;
  const int quar  = (int)blockIdx.x & 3;
  const int u0 = uTile * 64;
  const int ib = quar * 2048;
  const int lr = lane & 15, lg = lane >> 4, l16 = lane & 15;
  const float mA2 = fdec(mxenc[0]);

  // MFMA-row constants (row = u0 + wm*16 + lr)
  const int rowm = u0 + wm * 16 + lr;
  const float Am  = a1g[rowm];
  const float Cm  = lrelu(Am + mA2);
  const float K1m = __expf(Am - Cm);
  const float K2m = __expf(0.2f * Am - Cm);
  const float T1m = __expf(-Am);
  const unsigned* mrow = mask + (size_t)rowm * 256 + quar * 64;

  // store-phase row constants: rows rs0 = u0+wv*8+(lane>>4), rs1 = rs0+4
  const int rs0 = u0 + wv * 8 + (lane >> 4);
  const int rs1 = rs0 + 4;
  const float As0 = a1g[rs0], As1 = a1g[rs1];
  const float Cs0 = lrelu(As0 + mA2), Cs1 = lrelu(As1 + mA2);
  const float ri0 = rinv[rs0], ri1 = rinv[rs1];
  const float K1s0 = __expf(As0 - Cs0) * ri0, K1s1 = __expf(As1 - Cs1) * ri1;
  const float K2s0 = __expf(0.2f * As0 - Cs0) * ri0, K2s1 = __expf(0.2f * As1 - Cs1) * ri1;
  const float T1s0 = __expf(-As0), T1s1 = __expf(-As1);
  const unsigned* ms0 = mask + (size_t)rs0 * 256 + quar * 64;
  const unsigned* ms1 = mask + (size_t)rs1 * 256 + quar * 64;
  float* ap0 = alphap + (size_t)rs0 * NI + ib;
  float* ap1 = alphap + (size_t)rs1 * NI + ib;

  // staging map: thread covers (d = tid>>3 and d+64, i8 = tid&7)
  const int sd = tid >> 3;
  const int si = tid & 7;
  const short* g0 = WiT + (size_t)sd * NI + ib + si * 8;
  const short* g1 = WiT + (size_t)(sd + 64) * NI + ib + si * 8;
  const int swz = (si * 16) ^ ((sd & 7) << 4);
  const int w0 = sd * 128 + swz;
  const int w1 = (sd + 64) * 128 + swz;

  fx4 acc[4];
#pragma unroll
  for (int n = 0; n < 4; ++n) acc[n] = (fx4){0.f, 0.f, 0.f, 0.f};

  // prolog: stage chunk 0 into buf0
  bx8 sA = *(const bx8*)g0;
  bx8 sB = *(const bx8*)g1;
  *(bx8*)(lds + w0) = sA;
  *(bx8*)(lds + w1) = sB;

  for (int c = 0; c < 32; ++c) {
    char* buf = lds + (c & 1) * 16384;
    const int nxt = ((c + 1) & 1) * 16384;
    if (c < 31) {                       // issue next-chunk loads early
      sA = *(const bx8*)(g0 + (c + 1) * 64);
      sB = *(const bx8*)(g1 + (c + 1) * 64);
    }
    __syncthreads();                    // buf[c&1] ready; prior reads of nxt done

    // ---- MFMA phase: 2 k-steps (no alpha store here) ----
#pragma unroll
    for (int ks = 0; ks < 2; ++ks) {
      const int ksg = c * 2 + ks;       // 0..63
      const unsigned by = (mrow[ksg] >> (lg * 8)) & 0xFFu;
      const int io = ksg * 32 + lg * 8;
      const fx4 e1a = *(const fx4*)(e1g + ib + io);
      const fx4 e1b = *(const fx4*)(e1g + ib + io + 4);
      const fx4 e2a = *(const fx4*)(e2g + ib + io);
      const fx4 e2b = *(const fx4*)(e2g + ib + io + 4);
      bx8 af;
#pragma unroll
      for (int j = 0; j < 8; ++j) {
        const float e1v = (j < 4) ? e1a[j] : e1b[j - 4];
        const float e2v = (j < 4) ? e2a[j] : e2b[j - 4];
        const float val = (e1v > T1m) ? e1v * K1m : e2v * K2m;
        af[j] = ((by >> j) & 1u) ? f2bf(val) : (short)0;
      }
#pragma unroll
      for (int nf = 0; nf < 4; ++nf) {
        const int d = wn2 * 64 + nf * 16 + lr;
        const bx8 bf = *(const bx8*)(buf + d * 128 +
                        ((ks * 64 + lg * 16) ^ ((lr & 7) << 4)));
        acc[nf] = __builtin_amdgcn_mfma_f32_16x16x32_bf16(af, bf, acc[nf], 0, 0, 0);
      }
    }

    // ---- Store phase: sector-clean normalized alpha (8 rows/wave, 256B runs) ----
    {
      const int co = c * 64 + l16 * 4;         // col offset within quarter
      const fx4 se1 = *(const fx4*)(e1g + ib + co);
      const fx4 se2 = *(const fx4*)(e2g + ib + co);
      const int wix = c * 2 + (l16 >> 3);
      const int sh  = (l16 & 7) * 4;
      const unsigned nib0 = (ms0[wix] >> sh) & 0xFu;
      const unsigned nib1 = (ms1[wix] >> sh) & 0xFu;
      fx4 o0, o1;
#pragma unroll
      for (int j = 0; j < 4; ++j) {
        const float v0 = (se1[j] > T1s0) ? se1[j] * K1s0 : se2[j] * K2s0;
        const float v1 = (se1[j] > T1s1) ? se1[j] * K1s1 : se2[j] * K2s1;
        o0[j] = ((nib0 >> j) & 1u) ? v0 : 0.f;
        o1[j] = ((nib1 >> j) & 1u) ? v1 : 0.f;
      }
      *(fx4*)(ap0 + co) = o0;
      *(fx4*)(ap1 + co) = o1;
    }

    if (c < 31) {                       // write next chunk
      *(bx8*)(lds + nxt + w0) = sA;
      *(bx8*)(lds + nxt + w1) = sB;
    }
  }

  // epilogue: waves own disjoint 16x64 tiles -> store partial directly
  float* pb = partial + (size_t)blockIdx.x * (64 * 128);
#pragma unroll
  for (int nf = 0; nf < 4; ++nf)
#pragma unroll
    for (int v = 0; v < 4; ++v)
      pb[(wm * 16 + lg * 4 + v) * 128 + wn2 * 64 + nf * 16 + lr] = acc[nf][v];
}

// ---- K5c: out[u][d] = (sum of 4 K-quarter partials) * rinv[u]
__global__ __launch_bounds__(512) void k_comb(
    const float* __restrict__ partial, const float* __restrict__ rinv,
    float* __restrict__ outp)
{
  const int g = blockIdx.x * 512 + threadIdx.x;   // 0..262143 (fx4 units)
  const int u = g >> 5;
  const int c4 = (g & 31) * 4;
  const int uTile = u >> 6, r = u & 63;
  const float* p0 = partial + ((size_t)uTile * 4) * 8192 + r * 128 + c4;
  fx4 s = *(const fx4*)p0;
#pragma unroll
  for (int q = 1; q < 4; ++q) {
    fx4 t = *(const fx4*)(p0 + (size_t)q * 8192);
    s[0] += t[0]; s[1] += t[1]; s[2] += t[2]; s[3] += t[3];
  }
  const float ri = rinv[u];
  fx4 o;
#pragma unroll
  for (int e = 0; e < 4; ++e) o[e] = s[e] * ri;
  *(fx4*)(outp + (size_t)u * DD + c4) = o;
}

extern "C" void kernel_launch(void* const* d_in, const int* in_sizes, int n_in,
                              void* d_out, int out_size, void* d_ws, size_t ws_size,
                              hipStream_t stream) {
  (void)in_sizes; (void)n_in; (void)out_size; (void)ws_size;
  const float* h_u = (const float*)d_in[0];
  const float* h_i = (const float*)d_in[1];
  const int*   adj = (const int*)d_in[2];
  const float* W   = (const float*)d_in[3];
  const float* a   = (const float*)d_in[4];

  float* outp   = (float*)d_out;                       // [8192][128]
  float* alphap = (float*)d_out + (size_t)NU * DD;     // [8192][8192]

  char* ws = (char*)d_ws;
  float*    v1    = (float*)(ws + 0);          // 128 f32
  float*    v2    = (float*)(ws + 512);        // 128 f32
  unsigned* mxenc = (unsigned*)(ws + 1024);    // 1 u32 (order-encoded max a2)
  float*    a1    = (float*)(ws + 4096);       // 8192 f32
  float*    a2    = (float*)(ws + 36864);      // 8192 f32
  float*    rinv  = (float*)(ws + 69632);      // 8192 f32
  float*    e1t   = (float*)(ws + 102400);     // 8192 f32: exp(a2)
  float*    e2t   = (float*)(ws + 135168);     // 8192 f32: exp(0.2 a2)
  short*    WiT   = (short*)(ws + 262144);     // 128*8192 bf16 = 2 MiB
  unsigned* mask  = (unsigned*)(ws + 2359296); // 8192*256 u32 = 8 MiB
  float*    part  = (float*)(ws + 11534336);   // 512*64*128 f32 = 16 MiB

  k_vecs   <<<1,    128, 0, stream>>>(W, a, v1, v2, mxenc);
  k_rowdots<<<64,   256, 0, stream>>>(h_u, h_i, v1, v2, a1, a2, e1t, e2t, mxenc);
  k_wit    <<<128,  256, 0, stream>>>(h_i, W, WiT);
  k_phaseA <<<4096, 512, 0, stream>>>(adj, a1, e1t, e2t, mxenc, rinv,
                                      (unsigned short*)mask);
  k_big    <<<512,  512, 0, stream>>>(mask, a1, e1t, e2t, mxenc, rinv, WiT,
                                      part, alphap);
  k_comb   <<<512,  512, 0, stream>>>(part, rinv, outp);
}

// Round 8
// 241.155 us; speedup vs baseline: 1.8438x; 1.8438x over previous
//
#include <hip/hip_runtime.h>

#define NU 8192
#define NI 8192
#define DD 128

typedef float fx4 __attribute__((ext_vector_type(4)));
typedef int   ix4 __attribute__((ext_vector_type(4)));
typedef short bx8 __attribute__((ext_vector_type(8)));
typedef short sx4 __attribute__((ext_vector_type(4)));

__device__ __forceinline__ short f2bf(float f) {
  unsigned u = __float_as_uint(f);
  u = (u + 0x7FFFu + ((u >> 16) & 1u)) >> 16;   // RNE f32 -> bf16
  return (short)u;
}
__device__ __forceinline__ float lrelu(float x) { return fmaxf(x, 0.2f * x); }
// order-preserving float<->uint encode for atomicMax (deterministic: max assoc/comm)
__device__ __forceinline__ unsigned fenc(float f) {
  unsigned u = __float_as_uint(f);
  return (u >> 31) ? ~u : (u | 0x80000000u);
}
__device__ __forceinline__ float fdec(unsigned u) {
  return (u >> 31) ? __uint_as_float(u & 0x7FFFFFFFu) : __uint_as_float(~u);
}

// ---- K2 (fused K1): per-block v1/v2 in LDS, then a1/a2/e-tables; atomicMax a2
__global__ __launch_bounds__(256) void k_rowdots(
    const float* __restrict__ hU, const float* __restrict__ hI,
    const float* __restrict__ W, const float* __restrict__ a,
    float* __restrict__ a1, float* __restrict__ a2,
    float* __restrict__ e1, float* __restrict__ e2,
    unsigned* __restrict__ mxenc) {
  __shared__ float vv[2][128];
  __shared__ float red[256];
  const int tid = threadIdx.x;
  if (tid < 128) {
    float s1 = 0.f, s2 = 0.f;
    for (int k = 0; k < DD; ++k) {
      float w = W[k * DD + tid];
      s1 += a[k] * w;
      s2 += a[DD + k] * w;
    }
    vv[0][tid] = s1; vv[1][tid] = s2;
  }
  __syncthreads();
  const int g = blockIdx.x * 256 + tid;
  const bool isU = (g < NU);
  const int row = isU ? g : g - NU;
  const float* h = isU ? hU : hI;
  const float* v = isU ? vv[0] : vv[1];
  const fx4* hv = (const fx4*)(h + (size_t)row * DD);
  const fx4* vq = (const fx4*)v;
  float s = 0.f;
#pragma unroll
  for (int q = 0; q < DD / 4; ++q) {
    fx4 hq = hv[q], vqq = vq[q];
    s += hq[0]*vqq[0] + hq[1]*vqq[1] + hq[2]*vqq[2] + hq[3]*vqq[3];
  }
  if (isU) { a1[row] = s; return; }           // blocks 0..31 all-user: uniform exit
  a2[row] = s;
  e1[row] = __expf(s);
  e2[row] = __expf(0.2f * s);
  red[tid] = s;
  __syncthreads();
  for (int st = 128; st > 0; st >>= 1) {
    if (tid < st) red[tid] = fmaxf(red[tid], red[tid + st]);
    __syncthreads();
  }
  if (tid == 0) atomicMax(mxenc, fenc(red[0]));
}

// ---- K4: WiT[k][i] (bf16) = Wi[i][k] = sum_j h_i[i][j]*W[k][j]
__global__ __launch_bounds__(256) void k_wit(const float* __restrict__ hI,
                                             const float* __restrict__ W,
                                             short* __restrict__ WiT) {
  __shared__ float Wl[128 * 128];
  const int tid = threadIdx.x;
#pragma unroll
  for (int it = 0; it < 16; ++it) {
    int idx = it * 1024 + tid * 4;
    *(fx4*)(Wl + idx) = *(const fx4*)(W + idx);
  }
  __syncthreads();
  const int i0 = blockIdx.x * 64;
  const int rg = tid & 15;
  const int kg = tid >> 4;
  const int r0 = i0 + rg * 4;
  const int k0 = kg * 8;
  float acc[4][8];
#pragma unroll
  for (int r = 0; r < 4; ++r)
#pragma unroll
    for (int c = 0; c < 8; ++c) acc[r][c] = 0.f;
  for (int j = 0; j < 128; j += 4) {
    fx4 wv[8], hv[4];
#pragma unroll
    for (int c = 0; c < 8; ++c) wv[c] = *(const fx4*)(Wl + (k0 + c) * 128 + j);
#pragma unroll
    for (int r = 0; r < 4; ++r) hv[r] = *(const fx4*)(hI + (size_t)(r0 + r) * DD + j);
#pragma unroll
    for (int r = 0; r < 4; ++r)
#pragma unroll
      for (int c = 0; c < 8; ++c)
        acc[r][c] += hv[r][0]*wv[c][0] + hv[r][1]*wv[c][1] + hv[r][2]*wv[c][2] + hv[r][3]*wv[c][3];
  }
#pragma unroll
  for (int c = 0; c < 8; ++c) {
    sx4 pk;
#pragma unroll
    for (int r = 0; r < 4; ++r) pk[r] = f2bf(acc[r][c]);
    *(sx4*)(WiT + (size_t)(k0 + c) * NI + r0) = pk;
  }
}

// ---- K5a v5: adj -> bitmask + kcons. 4 rows/block, grid 2048, deep MLP.
// kcons[row] = (K1*ri, K2*ri, T1, ri): all downstream consumers exp-free.
__global__ __launch_bounds__(512, 4) void k_phaseA(
    const int* __restrict__ adj, const float* __restrict__ a1g,
    const float* __restrict__ e1g, const float* __restrict__ e2g,
    const unsigned* __restrict__ mxenc,
    fx4* __restrict__ kcons, unsigned short* __restrict__ mask16)
{
  const int tid  = threadIdx.x;
  const int lane = tid & 63;
  const int wv   = tid >> 6;
  const int r0   = blockIdx.x * 4;
  const int i0   = tid * 16;
  const size_t b0 = (size_t)r0 * NI + i0;
  ix4 m0[4], m1[4], m2[4], m3[4];
  fx4 E1[4], E2[4];
#pragma unroll
  for (int q = 0; q < 4; ++q) m0[q] = *(const ix4*)(adj + b0 + q * 4);
#pragma unroll
  for (int q = 0; q < 4; ++q) m1[q] = *(const ix4*)(adj + b0 + NI + q * 4);
#pragma unroll
  for (int q = 0; q < 4; ++q) {
    E1[q] = *(const fx4*)(e1g + i0 + q * 4);
    E2[q] = *(const fx4*)(e2g + i0 + q * 4);
  }
#pragma unroll
  for (int q = 0; q < 4; ++q) m2[q] = *(const ix4*)(adj + b0 + 2 * (size_t)NI + q * 4);
#pragma unroll
  for (int q = 0; q < 4; ++q) m3[q] = *(const ix4*)(adj + b0 + 3 * (size_t)NI + q * 4);

  const float mA2 = fdec(mxenc[0]);
  float K1[4], K2[4], T1[4], ps[4];
#pragma unroll
  for (int r = 0; r < 4; ++r) {
    const float A = a1g[r0 + r];
    const float C = lrelu(A + mA2);
    K1[r] = __expf(A - C);
    K2[r] = __expf(0.2f * A - C);
    T1[r] = __expf(-A);          // sel <=> E1[i] > T1 <=> a1+a2 > 0
  }

#define PROC(MR, RI)                                                      \
  {                                                                       \
    unsigned hw = 0u; float s1 = 0.f, s2 = 0.f;                           \
    _Pragma("unroll")                                                     \
    for (int q = 0; q < 4; ++q) {                                         \
      _Pragma("unroll")                                                   \
      for (int e = 0; e < 4; ++e) {                                       \
        const float e1v = E1[q][e], e2v = E2[q][e];                       \
        const bool mm = (MR[q][e] != 0);                                  \
        const bool sel = (e1v > T1[RI]);                                  \
        if (mm) hw |= (1u << (q * 4 + e));                                \
        s1 += (mm && sel)  ? e1v : 0.f;                                   \
        s2 += (mm && !sel) ? e2v : 0.f;                                   \
      }                                                                   \
    }                                                                     \
    mask16[(size_t)(r0 + RI) * 512 + tid] = (unsigned short)hw;           \
    ps[RI] = K1[RI] * s1 + K2[RI] * s2;                                   \
  }
  PROC(m0, 0) PROC(m1, 1) PROC(m2, 2) PROC(m3, 3)
#undef PROC

#pragma unroll
  for (int st = 1; st < 64; st <<= 1) {
    ps[0] += __shfl_xor(ps[0], st, 64);
    ps[1] += __shfl_xor(ps[1], st, 64);
    ps[2] += __shfl_xor(ps[2], st, 64);
    ps[3] += __shfl_xor(ps[3], st, 64);
  }
  __shared__ float lp[4][8];
  if (lane == 0) { lp[0][wv] = ps[0]; lp[1][wv] = ps[1]; lp[2][wv] = ps[2]; lp[3][wv] = ps[3]; }
  __syncthreads();
  if (tid < 4) {
    float l = 0.f;
#pragma unroll
    for (int w = 0; w < 8; ++w) l += lp[tid][w];
    const float ri = (l > 0.f) ? (1.f / l) : 0.f;
    const float k1s = (tid == 0) ? K1[0] : (tid == 1) ? K1[1] : (tid == 2) ? K1[2] : K1[3];
    const float k2s = (tid == 0) ? K2[0] : (tid == 1) ? K2[1] : (tid == 2) ? K2[2] : K2[3];
    const float t1s = (tid == 0) ? T1[0] : (tid == 1) ? T1[1] : (tid == 2) ? T1[2] : T1[3];
    kcons[r0 + tid] = (fx4){k1s * ri, k2s * ri, t1s, ri};
  }
}

// ---- K5b: fused alpha + out-partial GEMM, LDS-staged B, 1KB-burst alpha stores.
// grid 512 = 128 uTiles x 4 K-quarters; 512 thr (8 waves = 4 wm x 2 wn2).
// Block: rows u0..u0+64, i-range quar*2048..+2048. BK=64, 32 chunks, dbuf LDS 32KB.
// Alpha: every 4 chunks each wave stores 8 rows x 1KB contiguous (1 instr/row).
__global__ __launch_bounds__(512, 4) void k_big(
    const unsigned* __restrict__ mask, const fx4* __restrict__ kcons,
    const float* __restrict__ e1g, const float* __restrict__ e2g,
    const short* __restrict__ WiT, float* __restrict__ partial,
    float* __restrict__ alphap)
{
  __shared__ __align__(16) char lds[32768];
  const int tid  = threadIdx.x;
  const int lane = tid & 63;
  const int wv   = tid >> 6;
  const int wm   = wv & 3;         // m-frag (16 rows each)
  const int wn2  = wv >> 2;        // 0..1: n-half (64 cols each)
  const int uTile = (int)blockIdx.x >> 2;
  const int quar  = (int)blockIdx.x & 3;
  const int u0 = uTile * 64;
  const int ib = quar * 2048;
  const int lr = lane & 15, lg = lane >> 4;

  // MFMA-row constants (row = u0 + wm*16 + lr) — pre-normalized
  const int rowm = u0 + wm * 16 + lr;
  const fx4 kcm = kcons[rowm];
  const float K1m = kcm[0], K2m = kcm[1], T1m = kcm[2];
  const unsigned* mrow = mask + (size_t)rowm * 256 + quar * 64;

  // store rows: 8 rows u0+wv*8 .. +8
  const int srow0 = u0 + wv * 8;

  // staging map: thread covers (d = tid>>3 and d+64, i8 = tid&7)
  const int sd = tid >> 3;
  const int si = tid & 7;
  const short* g0 = WiT + (size_t)sd * NI + ib + si * 8;
  const short* g1 = WiT + (size_t)(sd + 64) * NI + ib + si * 8;
  const int swz = (si * 16) ^ ((sd & 7) << 4);
  const int w0 = sd * 128 + swz;
  const int w1 = (sd + 64) * 128 + swz;

  fx4 acc[4];
#pragma unroll
  for (int n = 0; n < 4; ++n) acc[n] = (fx4){0.f, 0.f, 0.f, 0.f};

  // prolog: stage chunk 0 into buf0
  bx8 sA = *(const bx8*)g0;
  bx8 sB = *(const bx8*)g1;
  *(bx8*)(lds + w0) = sA;
  *(bx8*)(lds + w1) = sB;

  for (int c = 0; c < 32; ++c) {
    char* buf = lds + (c & 1) * 16384;
    const int nxt = ((c + 1) & 1) * 16384;
    if (c < 31) {                       // issue next-chunk loads early
      sA = *(const bx8*)(g0 + (c + 1) * 64);
      sB = *(const bx8*)(g1 + (c + 1) * 64);
    }
    __syncthreads();                    // buf[c&1] ready; prior reads of nxt done

    // ---- MFMA phase: 2 k-steps ----
#pragma unroll
    for (int ks = 0; ks < 2; ++ks) {
      const int ksg = c * 2 + ks;       // 0..63
      const unsigned by = (mrow[ksg] >> (lg * 8)) & 0xFFu;
      const int io = ksg * 32 + lg * 8;
      const fx4 e1a = *(const fx4*)(e1g + ib + io);
      const fx4 e1b = *(const fx4*)(e1g + ib + io + 4);
      const fx4 e2a = *(const fx4*)(e2g + ib + io);
      const fx4 e2b = *(const fx4*)(e2g + ib + io + 4);
      bx8 af;
#pragma unroll
      for (int j = 0; j < 8; ++j) {
        const float e1v = (j < 4) ? e1a[j] : e1b[j - 4];
        const float e2v = (j < 4) ? e2a[j] : e2b[j - 4];
        const float val = (e1v > T1m) ? e1v * K1m : e2v * K2m;
        af[j] = ((by >> j) & 1u) ? f2bf(val) : (short)0;
      }
#pragma unroll
      for (int nf = 0; nf < 4; ++nf) {
        const int d = wn2 * 64 + nf * 16 + lr;
        const bx8 bf = *(const bx8*)(buf + d * 128 +
                        ((ks * 64 + lg * 16) ^ ((lr & 7) << 4)));
        acc[nf] = __builtin_amdgcn_mfma_f32_16x16x32_bf16(af, bf, acc[nf], 0, 0, 0);
      }
    }

    // ---- Alpha burst: every 4 chunks, 8 rows x 1KB contiguous per wave ----
    if ((c & 3) == 3) {
      const int co0 = (c - 3) * 64;             // 256-col window (quarter-local)
      const int col = co0 + lane * 4;
      const fx4 se1 = *(const fx4*)(e1g + ib + col);
      const fx4 se2 = *(const fx4*)(e2g + ib + col);
      const int wix = quar * 64 + (col >> 5);
      const int sh  = (lane & 7) * 4;
#pragma unroll
      for (int r = 0; r < 8; ++r) {
        const int row = srow0 + r;
        const fx4 kr = kcons[row];
        const unsigned nib = (mask[(size_t)row * 256 + wix] >> sh) & 0xFu;
        fx4 o;
#pragma unroll
        for (int j = 0; j < 4; ++j) {
          const float val = (se1[j] > kr[2]) ? se1[j] * kr[0] : se2[j] * kr[1];
          o[j] = ((nib >> j) & 1u) ? val : 0.f;
        }
        *(fx4*)(alphap + (size_t)row * NI + ib + col) = o;
      }
    }

    if (c < 31) {                       // write next chunk
      *(bx8*)(lds + nxt + w0) = sA;
      *(bx8*)(lds + nxt + w1) = sB;
    }
  }

  // epilogue: waves own disjoint 16x64 tiles -> store partial directly
  float* pb = partial + (size_t)blockIdx.x * (64 * 128);
#pragma unroll
  for (int nf = 0; nf < 4; ++nf)
#pragma unroll
    for (int v = 0; v < 4; ++v)
      pb[(wm * 16 + lg * 4 + v) * 128 + wn2 * 64 + nf * 16 + lr] = acc[nf][v];
}

// ---- K5c: out[u][d] = sum of 4 K-quarter partials (already normalized)
__global__ __launch_bounds__(512) void k_comb(
    const float* __restrict__ partial, float* __restrict__ outp)
{
  const int g = blockIdx.x * 512 + threadIdx.x;   // 0..262143 (fx4 units)
  const int u = g >> 5;
  const int c4 = (g & 31) * 4;
  const int uTile = u >> 6, r = u & 63;
  const float* p0 = partial + ((size_t)uTile * 4) * 8192 + r * 128 + c4;
  fx4 s = *(const fx4*)p0;
#pragma unroll
  for (int q = 1; q < 4; ++q) {
    fx4 t = *(const fx4*)(p0 + (size_t)q * 8192);
    s[0] += t[0]; s[1] += t[1]; s[2] += t[2]; s[3] += t[3];
  }
  *(fx4*)(outp + (size_t)u * DD + c4) = s;
}

extern "C" void kernel_launch(void* const* d_in, const int* in_sizes, int n_in,
                              void* d_out, int out_size, void* d_ws, size_t ws_size,
                              hipStream_t stream) {
  (void)in_sizes; (void)n_in; (void)out_size; (void)ws_size;
  const float* h_u = (const float*)d_in[0];
  const float* h_i = (const float*)d_in[1];
  const int*   adj = (const int*)d_in[2];
  const float* W   = (const float*)d_in[3];
  const float* a   = (const float*)d_in[4];

  float* outp   = (float*)d_out;                       // [8192][128]
  float* alphap = (float*)d_out + (size_t)NU * DD;     // [8192][8192]

  char* ws = (char*)d_ws;
  unsigned* mxenc = (unsigned*)(ws + 1024);    // 1 u32 (order-encoded max a2)
  float*    a1    = (float*)(ws + 4096);       // 8192 f32
  float*    a2    = (float*)(ws + 36864);      // 8192 f32
  float*    e1t   = (float*)(ws + 102400);     // 8192 f32: exp(a2)
  float*    e2t   = (float*)(ws + 135168);     // 8192 f32: exp(0.2 a2)
  short*    WiT   = (short*)(ws + 262144);     // 128*8192 bf16 = 2 MiB
  unsigned* mask  = (unsigned*)(ws + 2359296); // 8192*256 u32 = 8 MiB
  float*    part  = (float*)(ws + 11534336);   // 512*64*128 f32 = 16 MiB
  fx4*      kcons = (fx4*)(ws + 29360128);     // 8192 fx4 = 128 KiB

  hipMemsetAsync(mxenc, 0, 4, stream);
  k_wit    <<<128,  256, 0, stream>>>(h_i, W, WiT);
  k_rowdots<<<64,   256, 0, stream>>>(h_u, h_i, W, a, a1, a2, e1t, e2t, mxenc);
  k_phaseA <<<2048, 512, 0, stream>>>(adj, a1, e1t, e2t, mxenc, kcons,
                                      (unsigned short*)mask);
  k_big    <<<512,  512, 0, stream>>>(mask, kcons, e1t, e2t, WiT, part, alphap);
  k_comb   <<<512,  512, 0, stream>>>(part, outp);
}

// Round 9
// 213.080 us; speedup vs baseline: 2.0868x; 1.1318x over previous
//
#include <hip/hip_runtime.h>

#define NU 8192
#define NI 8192
#define DD 128

typedef float fx4 __attribute__((ext_vector_type(4)));
typedef int   ix4 __attribute__((ext_vector_type(4)));
typedef short bx8 __attribute__((ext_vector_type(8)));
typedef short sx4 __attribute__((ext_vector_type(4)));

__device__ __forceinline__ short f2bf(float f) {
  unsigned u = __float_as_uint(f);
  u = (u + 0x7FFFu + ((u >> 16) & 1u)) >> 16;   // RNE f32 -> bf16
  return (short)u;
}
__device__ __forceinline__ float lrelu(float x) { return fmaxf(x, 0.2f * x); }
// order-preserving float<->uint encode for atomicMax (deterministic: max assoc/comm)
__device__ __forceinline__ unsigned fenc(float f) {
  unsigned u = __float_as_uint(f);
  return (u >> 31) ? ~u : (u | 0x80000000u);
}
__device__ __forceinline__ float fdec(unsigned u) {
  return (u >> 31) ? __uint_as_float(u & 0x7FFFFFFFu) : __uint_as_float(~u);
}

// ---- K0: init the encoded-max cell
__global__ void k_init(unsigned* __restrict__ mxenc) { mxenc[0] = 0u; }

// ---- K2 (fused K1): per-block v1/v2 in LDS, then a1/a2/e-tables; atomicMax a2
__global__ __launch_bounds__(256) void k_rowdots(
    const float* __restrict__ hU, const float* __restrict__ hI,
    const float* __restrict__ W, const float* __restrict__ a,
    float* __restrict__ a1, float* __restrict__ a2,
    float* __restrict__ e1, float* __restrict__ e2,
    unsigned* __restrict__ mxenc) {
  __shared__ float vv[2][128];
  __shared__ float red[256];
  const int tid = threadIdx.x;
  if (tid < 128) {
    float s1 = 0.f, s2 = 0.f;
    for (int k = 0; k < DD; ++k) {
      float w = W[k * DD + tid];
      s1 += a[k] * w;
      s2 += a[DD + k] * w;
    }
    vv[0][tid] = s1; vv[1][tid] = s2;
  }
  __syncthreads();
  const int g = blockIdx.x * 256 + tid;
  const bool isU = (g < NU);
  const int row = isU ? g : g - NU;
  const float* h = isU ? hU : hI;
  const float* v = isU ? vv[0] : vv[1];
  const fx4* hv = (const fx4*)(h + (size_t)row * DD);
  const fx4* vq = (const fx4*)v;
  float s = 0.f;
#pragma unroll
  for (int q = 0; q < DD / 4; ++q) {
    fx4 hq = hv[q], vqq = vq[q];
    s += hq[0]*vqq[0] + hq[1]*vqq[1] + hq[2]*vqq[2] + hq[3]*vqq[3];
  }
  if (isU) { a1[row] = s; return; }           // blocks 0..31 all-user: uniform exit
  a2[row] = s;
  e1[row] = __expf(s);
  e2[row] = __expf(0.2f * s);
  red[tid] = s;
  __syncthreads();
  for (int st = 128; st > 0; st >>= 1) {
    if (tid < st) red[tid] = fmaxf(red[tid], red[tid + st]);
    __syncthreads();
  }
  if (tid == 0) atomicMax(mxenc, fenc(red[0]));
}

// ---- K4: WiT[k][i] (bf16) = Wi[i][k] = sum_j h_i[i][j]*W[k][j]
__global__ __launch_bounds__(256) void k_wit(const float* __restrict__ hI,
                                             const float* __restrict__ W,
                                             short* __restrict__ WiT) {
  __shared__ float Wl[128 * 128];
  const int tid = threadIdx.x;
#pragma unroll
  for (int it = 0; it < 16; ++it) {
    int idx = it * 1024 + tid * 4;
    *(fx4*)(Wl + idx) = *(const fx4*)(W + idx);
  }
  __syncthreads();
  const int i0 = blockIdx.x * 64;
  const int rg = tid & 15;
  const int kg = tid >> 4;
  const int r0 = i0 + rg * 4;
  const int k0 = kg * 8;
  float acc[4][8];
#pragma unroll
  for (int r = 0; r < 4; ++r)
#pragma unroll
    for (int c = 0; c < 8; ++c) acc[r][c] = 0.f;
  for (int j = 0; j < 128; j += 4) {
    fx4 wv[8], hv[4];
#pragma unroll
    for (int c = 0; c < 8; ++c) wv[c] = *(const fx4*)(Wl + (k0 + c) * 128 + j);
#pragma unroll
    for (int r = 0; r < 4; ++r) hv[r] = *(const fx4*)(hI + (size_t)(r0 + r) * DD + j);
#pragma unroll
    for (int r = 0; r < 4; ++r)
#pragma unroll
      for (int c = 0; c < 8; ++c)
        acc[r][c] += hv[r][0]*wv[c][0] + hv[r][1]*wv[c][1] + hv[r][2]*wv[c][2] + hv[r][3]*wv[c][3];
  }
#pragma unroll
  for (int c = 0; c < 8; ++c) {
    sx4 pk;
#pragma unroll
    for (int r = 0; r < 4; ++r) pk[r] = f2bf(acc[r][c]);
    *(sx4*)(WiT + (size_t)(k0 + c) * NI + r0) = pk;
  }
}

// ---- K5a v6: adj -> bitmask + kcons. 1 row/block, 256 thr, 6 blocks/CU.
// Perfectly coalesced: instruction q covers i = q*1024 + [lane-contiguous 4B*4].
// Mask repacked to [row][256] u32 (bit b of word w <=> i = 32w+b) via ballot+spread.
__global__ __launch_bounds__(256, 6) void k_phaseA(
    const int* __restrict__ adj, const float* __restrict__ a1g,
    const float* __restrict__ e1g, const float* __restrict__ e2g,
    const unsigned* __restrict__ mxenc,
    fx4* __restrict__ kcons, unsigned* __restrict__ mask)
{
  const int row  = blockIdx.x;
  const int tid  = threadIdx.x;
  const int lane = tid & 63;
  const int wv   = tid >> 6;       // 0..3
  const size_t base = (size_t)row * NI;
  ix4 m[8];
#pragma unroll
  for (int q = 0; q < 8; ++q)
    m[q] = __builtin_nontemporal_load((const ix4*)(adj + base + q * 1024 + tid * 4));
  const float A  = a1g[row];
  const float C  = lrelu(A + fdec(mxenc[0]));
  const float K1 = __expf(A - C);
  const float K2 = __expf(0.2f * A - C);
  const float T1 = __expf(-A);     // sel <=> E1[i] > T1 <=> a1+a2 > 0
  float s1 = 0.f, s2 = 0.f;
#pragma unroll
  for (int q = 0; q < 8; ++q) {
    const int i0 = q * 1024 + tid * 4;
    const fx4 E1 = *(const fx4*)(e1g + i0);
    const fx4 E2 = *(const fx4*)(e2g + i0);
    unsigned long long b[4];
#pragma unroll
    for (int e = 0; e < 4; ++e) {
      const bool mm  = (m[q][e] != 0);
      const bool sel = (E1[e] > T1);
      s1 += (mm && sel)  ? E1[e] : 0.f;
      s2 += (mm && !sel) ? E2[e] : 0.f;
      b[e] = __ballot(mm);
    }
    if (lane < 8) {
      unsigned w = 0u;
#pragma unroll
      for (int e = 0; e < 4; ++e) {
        unsigned x = (unsigned)((b[e] >> (lane * 8)) & 0xFFull);
        x = (x | (x << 12)) & 0x000F000Fu;    // spread 8 bits -> every 4th bit
        x = (x | (x << 6))  & 0x03030303u;
        x = (x | (x << 3))  & 0x11111111u;
        w |= x << e;
      }
      mask[(size_t)row * 256 + q * 32 + wv * 8 + lane] = w;
    }
  }
  float ps = K1 * s1 + K2 * s2;
#pragma unroll
  for (int st = 1; st < 64; st <<= 1) ps += __shfl_xor(ps, st, 64);
  __shared__ float lp[4];
  if (lane == 0) lp[wv] = ps;
  __syncthreads();
  if (tid == 0) {
    const float l = lp[0] + lp[1] + lp[2] + lp[3];
    const float ri = (l > 0.f) ? (1.f / l) : 0.f;
    kcons[row] = (fx4){K1 * ri, K2 * ri, T1, ri};
  }
}

// ---- K5b: fused alpha + out-partial GEMM, LDS-staged B, 1KB-burst alpha stores.
// grid 512 = 128 uTiles x 4 K-quarters; 512 thr (8 waves = 4 wm x 2 wn2).
__global__ __launch_bounds__(512, 4) void k_big(
    const unsigned* __restrict__ mask, const fx4* __restrict__ kcons,
    const float* __restrict__ e1g, const float* __restrict__ e2g,
    const short* __restrict__ WiT, float* __restrict__ partial,
    float* __restrict__ alphap)
{
  __shared__ __align__(16) char lds[32768];
  const int tid  = threadIdx.x;
  const int lane = tid & 63;
  const int wv   = tid >> 6;
  const int wm   = wv & 3;         // m-frag (16 rows each)
  const int wn2  = wv >> 2;        // 0..1: n-half (64 cols each)
  const int uTile = (int)blockIdx.x >> 2;
  const int quar  = (int)blockIdx.x & 3;
  const int u0 = uTile * 64;
  const int ib = quar * 2048;
  const int lr = lane & 15, lg = lane >> 4;

  // MFMA-row constants (row = u0 + wm*16 + lr) — pre-normalized
  const int rowm = u0 + wm * 16 + lr;
  const fx4 kcm = kcons[rowm];
  const float K1m = kcm[0], K2m = kcm[1], T1m = kcm[2];
  const unsigned* mrow = mask + (size_t)rowm * 256 + quar * 64;

  // store rows: 8 rows u0+wv*8 .. +8
  const int srow0 = u0 + wv * 8;

  // staging map: thread covers (d = tid>>3 and d+64, i8 = tid&7)
  const int sd = tid >> 3;
  const int si = tid & 7;
  const short* g0 = WiT + (size_t)sd * NI + ib + si * 8;
  const short* g1 = WiT + (size_t)(sd + 64) * NI + ib + si * 8;
  const int swz = (si * 16) ^ ((sd & 7) << 4);
  const int w0 = sd * 128 + swz;
  const int w1 = (sd + 64) * 128 + swz;

  fx4 acc[4];
#pragma unroll
  for (int n = 0; n < 4; ++n) acc[n] = (fx4){0.f, 0.f, 0.f, 0.f};

  // prolog: stage chunk 0 into buf0
  bx8 sA = *(const bx8*)g0;
  bx8 sB = *(const bx8*)g1;
  *(bx8*)(lds + w0) = sA;
  *(bx8*)(lds + w1) = sB;

  for (int c = 0; c < 32; ++c) {
    char* buf = lds + (c & 1) * 16384;
    const int nxt = ((c + 1) & 1) * 16384;
    if (c < 31) {                       // issue next-chunk loads early
      sA = *(const bx8*)(g0 + (c + 1) * 64);
      sB = *(const bx8*)(g1 + (c + 1) * 64);
    }
    __syncthreads();                    // buf[c&1] ready; prior reads of nxt done

    // ---- MFMA phase: 2 k-steps ----
#pragma unroll
    for (int ks = 0; ks < 2; ++ks) {
      const int ksg = c * 2 + ks;       // 0..63
      const unsigned by = (mrow[ksg] >> (lg * 8)) & 0xFFu;
      const int io = ksg * 32 + lg * 8;
      const fx4 e1a = *(const fx4*)(e1g + ib + io);
      const fx4 e1b = *(const fx4*)(e1g + ib + io + 4);
      const fx4 e2a = *(const fx4*)(e2g + ib + io);
      const fx4 e2b = *(const fx4*)(e2g + ib + io + 4);
      bx8 af;
#pragma unroll
      for (int j = 0; j < 8; ++j) {
        const float e1v = (j < 4) ? e1a[j] : e1b[j - 4];
        const float e2v = (j < 4) ? e2a[j] : e2b[j - 4];
        const float val = (e1v > T1m) ? e1v * K1m : e2v * K2m;
        af[j] = ((by >> j) & 1u) ? f2bf(val) : (short)0;
      }
#pragma unroll
      for (int nf = 0; nf < 4; ++nf) {
        const int d = wn2 * 64 + nf * 16 + lr;
        const bx8 bf = *(const bx8*)(buf + d * 128 +
                        ((ks * 64 + lg * 16) ^ ((lr & 7) << 4)));
        acc[nf] = __builtin_amdgcn_mfma_f32_16x16x32_bf16(af, bf, acc[nf], 0, 0, 0);
      }
    }

    // ---- Alpha burst: every 4 chunks, 8 rows x 1KB contiguous per wave ----
    if ((c & 3) == 3) {
      const int co0 = (c - 3) * 64;             // 256-col window (quarter-local)
      const int col = co0 + lane * 4;
      const fx4 se1 = *(const fx4*)(e1g + ib + col);
      const fx4 se2 = *(const fx4*)(e2g + ib + col);
      const int wix = quar * 64 + (col >> 5);
      const int sh  = (lane & 7) * 4;
#pragma unroll
      for (int r = 0; r < 8; ++r) {
        const int row = srow0 + r;
        const fx4 kr = kcons[row];
        const unsigned nib = (mask[(size_t)row * 256 + wix] >> sh) & 0xFu;
        fx4 o;
#pragma unroll
        for (int j = 0; j < 4; ++j) {
          const float val = (se1[j] > kr[2]) ? se1[j] * kr[0] : se2[j] * kr[1];
          o[j] = ((nib >> j) & 1u) ? val : 0.f;
        }
        *(fx4*)(alphap + (size_t)row * NI + ib + col) = o;
      }
    }

    if (c < 31) {                       // write next chunk
      *(bx8*)(lds + nxt + w0) = sA;
      *(bx8*)(lds + nxt + w1) = sB;
    }
  }

  // epilogue: waves own disjoint 16x64 tiles -> store partial directly
  float* pb = partial + (size_t)blockIdx.x * (64 * 128);
#pragma unroll
  for (int nf = 0; nf < 4; ++nf)
#pragma unroll
    for (int v = 0; v < 4; ++v)
      pb[(wm * 16 + lg * 4 + v) * 128 + wn2 * 64 + nf * 16 + lr] = acc[nf][v];
}

// ---- K5c: out[u][d] = sum of 4 K-quarter partials (already normalized)
__global__ __launch_bounds__(512) void k_comb(
    const float* __restrict__ partial, float* __restrict__ outp)
{
  const int g = blockIdx.x * 512 + threadIdx.x;   // 0..262143 (fx4 units)
  const int u = g >> 5;
  const int c4 = (g & 31) * 4;
  const int uTile = u >> 6, r = u & 63;
  const float* p0 = partial + ((size_t)uTile * 4) * 8192 + r * 128 + c4;
  fx4 s = *(const fx4*)p0;
#pragma unroll
  for (int q = 1; q < 4; ++q) {
    fx4 t = *(const fx4*)(p0 + (size_t)q * 8192);
    s[0] += t[0]; s[1] += t[1]; s[2] += t[2]; s[3] += t[3];
  }
  *(fx4*)(outp + (size_t)u * DD + c4) = s;
}

extern "C" void kernel_launch(void* const* d_in, const int* in_sizes, int n_in,
                              void* d_out, int out_size, void* d_ws, size_t ws_size,
                              hipStream_t stream) {
  (void)in_sizes; (void)n_in; (void)out_size; (void)ws_size;
  const float* h_u = (const float*)d_in[0];
  const float* h_i = (const float*)d_in[1];
  const int*   adj = (const int*)d_in[2];
  const float* W   = (const float*)d_in[3];
  const float* a   = (const float*)d_in[4];

  float* outp   = (float*)d_out;                       // [8192][128]
  float* alphap = (float*)d_out + (size_t)NU * DD;     // [8192][8192]

  char* ws = (char*)d_ws;
  unsigned* mxenc = (unsigned*)(ws + 1024);    // 1 u32 (order-encoded max a2)
  float*    a1    = (float*)(ws + 4096);       // 8192 f32
  float*    a2    = (float*)(ws + 36864);      // 8192 f32
  float*    e1t   = (float*)(ws + 102400);     // 8192 f32: exp(a2)
  float*    e2t   = (float*)(ws + 135168);     // 8192 f32: exp(0.2 a2)
  short*    WiT   = (short*)(ws + 262144);     // 128*8192 bf16 = 2 MiB
  unsigned* mask  = (unsigned*)(ws + 2359296); // 8192*256 u32 = 8 MiB
  float*    part  = (float*)(ws + 11534336);   // 512*64*128 f32 = 16 MiB
  fx4*      kcons = (fx4*)(ws + 29360128);     // 8192 fx4 = 128 KiB

  k_init   <<<1,    1,   0, stream>>>(mxenc);
  k_rowdots<<<64,   256, 0, stream>>>(h_u, h_i, W, a, a1, a2, e1t, e2t, mxenc);
  k_wit    <<<128,  256, 0, stream>>>(h_i, W, WiT);
  k_phaseA <<<NU,   256, 0, stream>>>(adj, a1, e1t, e2t, mxenc, kcons, mask);
  k_big    <<<512,  512, 0, stream>>>(mask, kcons, e1t, e2t, WiT, part, alphap);
  k_comb   <<<512,  512, 0, stream>>>(part, outp);
}